// Round 6
// baseline (358.510 us; speedup 1.0000x reference)
//
#include <hip/hip_runtime.h>

// irreps: 256x0e + 128x1e + 64x2e ; x row = 960 fp32
// Persistent merged kernel with LDS double-buffer pipeline:
//   tile t:  bar -> GEMM1(buf cur) -> bar -> [issue raw x-loads for t+NB]
//            normact->H in-place(cur) -> bar -> GEMM2(cur)
//            -> cvt+write stage regs -> buf nxt -> store out(t) -> flip
// Stage prefetch lives in statically-indexed register arrays (NO pointer
// params -- R4's scratch bug). bf16 MFMA 16x16x32, A = x/H rows from LDS
// (XOR-swizzled), B = weight fragments streamed from L2.

typedef __bf16 v8bf  __attribute__((ext_vector_type(8)));
typedef float  v4f   __attribute__((ext_vector_type(4)));

__device__ __forceinline__ unsigned short f2bf(float x) {
    union { float f; unsigned u; } v; v.f = x;
    unsigned r = v.u + 0x7FFFu + ((v.u >> 16) & 1u);   // RNE (finite inputs)
    return (unsigned short)(r >> 16);
}
__device__ __forceinline__ unsigned pk2(float a, float b) {
    return (unsigned)f2bf(a) | ((unsigned)f2bf(b) << 16);
}

// Phi(n) = 0.5*(1+erf(n/sqrt(2))) = gelu(n)/n, n>=0.  A&S 7.1.26.
__device__ __forceinline__ float phi_from_sq(float s) {
    float n = __builtin_amdgcn_sqrtf(s);
    float z = n * 0.70710678118654752f;
    float t = __builtin_amdgcn_rcpf(fmaf(0.3275911f, z, 1.0f));
    float p = t * fmaf(t, fmaf(t, fmaf(t, fmaf(t, 1.061405429f, -1.453152027f),
                                       1.421413741f), -0.284496736f), 0.254829592f);
    float e = __builtin_amdgcn_exp2f(z * z * -1.4426950408889634f);
    return fmaf(p * e, -0.5f, 1.0f);
}

// --- pre-pass: W[u][w] fp32 -> WT[w][u] bf16, scaled by 1/sqrt(mul_in) -------
__global__ __launch_bounds__(256) void wt_prep(
    const float* __restrict__ w0, const float* __restrict__ w1,
    const float* __restrict__ w2, const float* __restrict__ w3,
    const float* __restrict__ w4, const float* __restrict__ w5,
    unsigned short* __restrict__ out)
{
    int t = blockIdx.x * 256 + threadIdx.x;
    if (t >= 172032) return;
    int s = (t < 65536) ? 0 : (t < 81920) ? 1 : (t < 86016) ? 2
          : (t < 151552) ? 3 : (t < 167936) ? 4 : 5;
    int base = (s == 0) ? 0 : (s == 1) ? 65536 : (s == 2) ? 81920
             : (s == 3) ? 86016 : (s == 4) ? 151552 : 167936;
    int lg   = (s == 0 || s == 3) ? 8 : (s == 1 || s == 4) ? 7 : 6;
    float scl = (s == 0 || s == 3) ? 0.0625f
              : (s == 1 || s == 4) ? 0.08838834764831845f : 0.125f;
    const float* p = (s == 0) ? w0 : (s == 1) ? w1 : (s == 2) ? w2
                   : (s == 3) ? w3 : (s == 4) ? w4 : w5;
    int loc = t - base;
    int w = loc >> lg;
    int u = loc & ((1 << lg) - 1);
    out[t] = f2bf(p[(u << lg) + w] * scl);
}

// --- persistent per-irrep pipelined worker -----------------------------------
// LDS (per buffer): bf16 planes [i][n(ROWS)][u(U)], XOR-swizzle ^((R&7)<<3).
template<int U, int D, int OFF, int ROWS>
__device__ __forceinline__ void irrep_pipe(
    const float* __restrict__ x,
    const unsigned short* __restrict__ wt0,
    const unsigned short* __restrict__ wt1,
    float* __restrict__ out,
    unsigned short* lds0, unsigned short* lds1,
    int t0, int NB)
{
    constexpr int NTILES = 65536 / ROWS;
    constexpr int MT   = (ROWS * D) / 16;  // m-tiles
    constexpr int NPW  = U / 64;           // n-tiles per wave (4 waves split n)
    constexpr int KT   = U / 32;           // k-steps
    constexpr int NR16 = ROWS / 16;        // 16-row groups per i-plane
    constexpr int SIT  = (D == 1) ? (ROWS * (U / 8)) / 256
                                  : (ROWS * (U / 2)) / 256;   // stage iters

    const int tid  = threadIdx.x;
    const int lane = tid & 63;
    const int wid  = tid >> 6;
    const int wcol = lane & 15;
    const int kcol = (lane >> 4) << 3;
    const int g4   = (lane >> 4) << 2;

    // stage prefetch registers -- statically indexed, captured by reference
    float4 s4[(D == 1) ? SIT * 2 : 1];
    float2 s2[(D  > 1) ? SIT * D : 1];

    auto issue = [&](int tile) {
        if constexpr (D == 1) {
            #pragma unroll
            for (int o = 0; o < SIT; ++o) {
                int oct = o * 256 + tid;
                int row = oct / (U / 8);
                int u0  = (oct % (U / 8)) * 8;
                const float4* p = reinterpret_cast<const float4*>(
                    x + (long)(tile * ROWS + row) * 960 + OFF + u0);
                s4[o * 2]     = p[0];
                s4[o * 2 + 1] = p[1];
            }
        } else {
            constexpr int PAIRS = U / 2;
            #pragma unroll
            for (int g = 0; g < SIT; ++g) {
                int gid = g * 256 + tid;
                int row = gid / PAIRS;
                int u0  = (gid % PAIRS) * 2;
                const float2* p = reinterpret_cast<const float2*>(
                    x + (long)(tile * ROWS + row) * 960 + OFF + u0 * D);
                #pragma unroll
                for (int j = 0; j < D; ++j) s2[g * D + j] = p[j];
            }
        }
    };

    auto write_stage = [&](unsigned short* buf) {
        if constexpr (D == 1) {
            #pragma unroll
            for (int o = 0; o < SIT; ++o) {
                int oct = o * 256 + tid;
                int row = oct / (U / 8);
                int u0  = (oct % (U / 8)) * 8;
                float4 fa = s4[o * 2], fb = s4[o * 2 + 1];
                uint2 lohi0, lohi1;
                lohi0.x = pk2(fa.x, fa.y); lohi0.y = pk2(fa.z, fa.w);
                lohi1.x = pk2(fb.x, fb.y); lohi1.y = pk2(fb.z, fb.w);
                int idx = (row * U + u0) ^ ((row & 7) << 3);
                uint4 v; v.x = lohi0.x; v.y = lohi0.y; v.z = lohi1.x; v.w = lohi1.y;
                *reinterpret_cast<uint4*>(&buf[idx]) = v;   // ds_write_b128
            }
        } else {
            constexpr int PAIRS = U / 2;
            #pragma unroll
            for (int g = 0; g < SIT; ++g) {
                int gid = g * 256 + tid;
                int row = gid / PAIRS;
                int u0  = (gid % PAIRS) * 2;
                float f[2 * D];
                #pragma unroll
                for (int j = 0; j < D; ++j) {
                    float2 q = s2[g * D + j];
                    f[2 * j] = q.x; f[2 * j + 1] = q.y;
                }
                #pragma unroll
                for (int i = 0; i < D; ++i) {
                    int R = i * ROWS + row;
                    int idx = (R * U + u0) ^ ((R & 7) << 3);
                    *reinterpret_cast<unsigned*>(&buf[idx]) = pk2(f[i], f[D + i]);
                }
            }
        }
    };

    v4f acc[MT][NPW];

    auto run_layer = [&](const unsigned short* __restrict__ wt,
                         const unsigned short* buf) {
        #pragma unroll
        for (int mt = 0; mt < MT; ++mt)
            #pragma unroll
            for (int nt = 0; nt < NPW; ++nt) {
                v4f z = {0.f, 0.f, 0.f, 0.f};
                acc[mt][nt] = z;
            }
        #pragma unroll
        for (int kt = 0; kt < KT; ++kt) {
            v8bf b[NPW];
            #pragma unroll
            for (int nt = 0; nt < NPW; ++nt) {
                int w = (wid * NPW + nt) * 16 + wcol;
                b[nt] = *reinterpret_cast<const v8bf*>(wt + w * U + kt * 32 + kcol);
            }
            #pragma unroll
            for (int mt = 0; mt < MT; ++mt) {
                int R = mt * 16 + wcol;
                int idx = (R * U + kt * 32 + kcol) ^ ((R & 7) << 3);
                v8bf a = *reinterpret_cast<const v8bf*>(&buf[idx]);
                #pragma unroll
                for (int nt = 0; nt < NPW; ++nt)
                    acc[mt][nt] = __builtin_amdgcn_mfma_f32_16x16x32_bf16(
                        a, b[nt], acc[mt][nt], 0, 0, 0);
            }
        }
    };

    // ---- prologue: blocking stage of first tile into lds0 ----
    int t = t0;
    issue(t);
    write_stage(lds0);
    unsigned short* cur = lds0;
    unsigned short* nxt = lds1;

    while (t < NTILES) {
        __syncthreads();                       // stage writes visible
        run_layer(wt0, cur);
        __syncthreads();                       // all x reads done

        int tn = t + NB;
        issue(tn < NTILES ? tn : t);           // prefetch next tile (clamped)

        // normact + H write in-place into cur
        #pragma unroll
        for (int nt = 0; nt < NPW; ++nt) {
            int w = (wid * NPW + nt) * 16 + wcol;
            #pragma unroll
            for (int h = 0; h < NR16; ++h) {
                #pragma unroll
                for (int r = 0; r < 4; ++r) {
                    float s = 0.f;
                    #pragma unroll
                    for (int i = 0; i < D; ++i) {
                        float v = acc[i * NR16 + h][nt][r];
                        s += v * v;
                    }
                    float fac = phi_from_sq(s);
                    int n = h * 16 + g4 + r;
                    #pragma unroll
                    for (int i = 0; i < D; ++i) {
                        int R = i * ROWS + n;
                        int idx = (R * U + w) ^ ((R & 7) << 3);
                        cur[idx] = f2bf(acc[i * NR16 + h][nt][r] * fac);
                    }
                }
            }
        }
        __syncthreads();                       // H visible

        run_layer(wt1, cur);

        write_stage(nxt);                      // stage regs -> other buffer

        // store out fp32 at out[n][OFF + w*D + i]
        #pragma unroll
        for (int nt = 0; nt < NPW; ++nt) {
            int w = (wid * NPW + nt) * 16 + wcol;
            #pragma unroll
            for (int h = 0; h < NR16; ++h) {
                #pragma unroll
                for (int r = 0; r < 4; ++r) {
                    int n = t * ROWS + h * 16 + g4 + r;
                    float* po = out + (long)n * 960 + OFF + w * D;
                    #pragma unroll
                    for (int i = 0; i < D; ++i)
                        po[i] = acc[i * NR16 + h][nt][r];
                }
            }
        }

        t = tn;
        unsigned short* tmp = cur; cur = nxt; nxt = tmp;
    }
}

// --- merged persistent kernel: contiguous type ranges, ~work-balanced --------
__global__ __launch_bounds__(256, 4) void fused_all(
    const float* __restrict__ x,
    const unsigned short* __restrict__ ws,
    float* __restrict__ out)
{
    __shared__ unsigned short lds[2][8192];   // 2 x 16 KB
    int bid = blockIdx.x;
    if (bid < 384)
        irrep_pipe<256, 1,   0, 32>(x, ws + 0,     ws + 86016,  out,
                                    lds[0], lds[1], bid, 384);
    else if (bid < 768)
        irrep_pipe<128, 3, 256, 16>(x, ws + 65536, ws + 151552, out,
                                    lds[0], lds[1], bid - 384, 384);
    else
        irrep_pipe< 64, 5, 640, 16>(x, ws + 81920, ws + 167936, out,
                                    lds[0], lds[1], bid - 768, 256);
}

extern "C" void kernel_launch(void* const* d_in, const int* in_sizes, int n_in,
                              void* d_out, int out_size, void* d_ws, size_t ws_size,
                              hipStream_t stream)
{
    const float* x  = (const float*)d_in[0];
    const float* W0 = (const float*)d_in[1];  // 256x256
    const float* W1 = (const float*)d_in[2];  // 128x128
    const float* W2 = (const float*)d_in[3];  // 64x64
    const float* W3 = (const float*)d_in[4];  // 256x256
    const float* W4 = (const float*)d_in[5];  // 128x128
    const float* W5 = (const float*)d_in[6];  // 64x64
    unsigned short* ws = (unsigned short*)d_ws;   // 344064 B of bf16 WT
    float* out = (float*)d_out;

    wt_prep<<<672, 256, 0, stream>>>(W0, W1, W2, W3, W4, W5, ws);
    fused_all<<<1024, 256, 0, stream>>>(x, ws, out);
}

// Round 7
// 250.344 us; speedup vs baseline: 1.4321x; 1.4321x over previous
//
#include <hip/hip_runtime.h>

// irreps: 256x0e + 128x1e + 64x2e ; x row = 960 fp32
// l=0: barrier-free wave-private path -- each wave computes 16 rows x 256 ch;
//      A-frags of x loaded DIRECTLY from global (contiguous 32B), H through a
//      wave-private XOR-swizzled LDS region, s_waitcnt only (no __syncthreads).
// l=1, l=2: R5 structure (32-row LDS-staged tiles, block barriers).

typedef __bf16 v8bf  __attribute__((ext_vector_type(8)));
typedef float  v4f   __attribute__((ext_vector_type(4)));
typedef unsigned short u16x8 __attribute__((ext_vector_type(8)));

__device__ __forceinline__ unsigned short f2bf(float x) {
    union { float f; unsigned u; } v; v.f = x;
    unsigned r = v.u + 0x7FFFu + ((v.u >> 16) & 1u);   // RNE (finite inputs)
    return (unsigned short)(r >> 16);
}
__device__ __forceinline__ unsigned pk2(float a, float b) {
    return (unsigned)f2bf(a) | ((unsigned)f2bf(b) << 16);
}

// Phi(n) = 0.5*(1+erf(n/sqrt(2))) = gelu(n)/n, n>=0.  A&S 7.1.26.
__device__ __forceinline__ float phi_from_sq(float s) {
    float n = __builtin_amdgcn_sqrtf(s);
    float z = n * 0.70710678118654752f;
    float t = __builtin_amdgcn_rcpf(fmaf(0.3275911f, z, 1.0f));
    float p = t * fmaf(t, fmaf(t, fmaf(t, fmaf(t, 1.061405429f, -1.453152027f),
                                       1.421413741f), -0.284496736f), 0.254829592f);
    float e = __builtin_amdgcn_exp2f(z * z * -1.4426950408889634f);
    return fmaf(p * e, -0.5f, 1.0f);
}

// --- pre-pass: W[u][w] fp32 -> WT[w][u] bf16, scaled by 1/sqrt(mul_in) -------
__global__ __launch_bounds__(256) void wt_prep(
    const float* __restrict__ w0, const float* __restrict__ w1,
    const float* __restrict__ w2, const float* __restrict__ w3,
    const float* __restrict__ w4, const float* __restrict__ w5,
    unsigned short* __restrict__ out)
{
    int t = blockIdx.x * 256 + threadIdx.x;
    if (t >= 172032) return;
    int s = (t < 65536) ? 0 : (t < 81920) ? 1 : (t < 86016) ? 2
          : (t < 151552) ? 3 : (t < 167936) ? 4 : 5;
    int base = (s == 0) ? 0 : (s == 1) ? 65536 : (s == 2) ? 81920
             : (s == 3) ? 86016 : (s == 4) ? 151552 : 167936;
    int lg   = (s == 0 || s == 3) ? 8 : (s == 1 || s == 4) ? 7 : 6;
    float scl = (s == 0 || s == 3) ? 0.0625f
              : (s == 1 || s == 4) ? 0.08838834764831845f : 0.125f;
    const float* p = (s == 0) ? w0 : (s == 1) ? w1 : (s == 2) ? w2
                   : (s == 3) ? w3 : (s == 4) ? w4 : w5;
    int loc = t - base;
    int w = loc >> lg;
    int u = loc & ((1 << lg) - 1);
    out[t] = f2bf(p[(u << lg) + w] * scl);
}

// --- l=0 barrier-free wave path ----------------------------------------------
// hbuf: wave-private 4096-elem (8 KB) LDS region. H tile [16][256] bf16,
// XOR-swizzled ^((R&7)<<3) to spread the stride-512B column reads.
__device__ __forceinline__ void l0_wave(
    const float* __restrict__ x,
    const unsigned short* __restrict__ wt0,
    const unsigned short* __restrict__ wt1,
    float* __restrict__ out,
    unsigned short* hbuf,
    int tile)
{
    const int lane = threadIdx.x & 63;
    const int wid  = threadIdx.x >> 6;
    const int l15  = lane & 15;
    const int oct  = lane >> 4;
    const int row0 = tile * 64 + wid * 16;

    v4f acc[16];
    #pragma unroll
    for (int nt = 0; nt < 16; ++nt) { v4f z = {0.f,0.f,0.f,0.f}; acc[nt] = z; }

    // ---- GEMM1: A = x rows (direct from global), B = WT0 fragments ----
    const float* xr = x + (long)(row0 + l15) * 960 + oct * 8;
    #pragma unroll
    for (int kt = 0; kt < 8; ++kt) {
        float4 xa = *reinterpret_cast<const float4*>(xr + kt * 32);
        float4 xb = *reinterpret_cast<const float4*>(xr + kt * 32 + 4);
        v8bf a = { (__bf16)xa.x, (__bf16)xa.y, (__bf16)xa.z, (__bf16)xa.w,
                   (__bf16)xb.x, (__bf16)xb.y, (__bf16)xb.z, (__bf16)xb.w };
        #pragma unroll
        for (int hf = 0; hf < 2; ++hf) {
            v8bf b[8];
            #pragma unroll
            for (int j = 0; j < 8; ++j) {
                int w = (hf * 8 + j) * 16 + l15;
                b[j] = *reinterpret_cast<const v8bf*>(wt0 + w * 256 + kt * 32 + oct * 8);
            }
            #pragma unroll
            for (int j = 0; j < 8; ++j)
                acc[hf * 8 + j] = __builtin_amdgcn_mfma_f32_16x16x32_bf16(
                    a, b[j], acc[hf * 8 + j], 0, 0, 0);
        }
    }

    // ---- normact + H -> wave-private LDS (transpose via C/D layout) ----
    #pragma unroll
    for (int nt = 0; nt < 16; ++nt) {
        int w = nt * 16 + l15;
        #pragma unroll
        for (int r = 0; r < 4; ++r) {
            float h   = acc[nt][r];
            float fac = phi_from_sq(h * h);
            int R   = oct * 4 + r;
            int idx = (R * 256 + w) ^ ((R & 7) << 3);
            hbuf[idx] = f2bf(h * fac);
        }
    }
    // wave-internal LDS dependency: drain ds_writes, pin ordering
    asm volatile("s_waitcnt lgkmcnt(0)" ::: "memory");
    __builtin_amdgcn_sched_barrier(0);

    // ---- GEMM2: A = H rows from LDS, B = WT1 fragments ----
    #pragma unroll
    for (int nt = 0; nt < 16; ++nt) { v4f z = {0.f,0.f,0.f,0.f}; acc[nt] = z; }
    #pragma unroll
    for (int kt = 0; kt < 8; ++kt) {
        int idx = (l15 * 256 + kt * 32 + oct * 8) ^ ((l15 & 7) << 3);
        v8bf a = *reinterpret_cast<const v8bf*>(&hbuf[idx]);
        #pragma unroll
        for (int hf = 0; hf < 2; ++hf) {
            v8bf b[8];
            #pragma unroll
            for (int j = 0; j < 8; ++j) {
                int w = (hf * 8 + j) * 16 + l15;
                b[j] = *reinterpret_cast<const v8bf*>(wt1 + w * 256 + kt * 32 + oct * 8);
            }
            #pragma unroll
            for (int j = 0; j < 8; ++j)
                acc[hf * 8 + j] = __builtin_amdgcn_mfma_f32_16x16x32_bf16(
                    a, b[j], acc[hf * 8 + j], 0, 0, 0);
        }
    }

    // ---- stores: per (nt,r) 16 lanes write 64B contiguous ----
    #pragma unroll
    for (int nt = 0; nt < 16; ++nt) {
        int w = nt * 16 + l15;
        #pragma unroll
        for (int r = 0; r < 4; ++r) {
            int n = row0 + oct * 4 + r;
            out[(long)n * 960 + w] = acc[nt][r];
        }
    }
}

// --- l=1 / l=2 worker: R5 structure (32-row LDS-staged tile, barriers) -------
template<int U, int D, int OFF>
__device__ __forceinline__ void irrep_block(
    const float* __restrict__ x,
    const unsigned short* __restrict__ wt0,
    const unsigned short* __restrict__ wt1,
    float* __restrict__ out,
    unsigned short* __restrict__ lds,
    int tile)
{
    constexpr int ROWS = 32;
    constexpr int MT   = (ROWS * D) / 16;
    constexpr int NPW  = U / 64;
    constexpr int KT   = U / 32;
    constexpr int NR16 = ROWS / 16;

    const int tid  = threadIdx.x;
    const int lane = tid & 63;
    const int wid  = tid >> 6;
    const int row0 = tile * ROWS;

    constexpr int PAIRS = U / 2;
    #pragma unroll
    for (int g = 0; g < (ROWS * PAIRS) / 256; ++g) {
        int gid = g * 256 + tid;
        int row = gid / PAIRS;
        int u0  = (gid % PAIRS) * 2;
        const float2* p = reinterpret_cast<const float2*>(
            x + (long)(row0 + row) * 960 + OFF + u0 * D);
        float f[2 * D];
        #pragma unroll
        for (int j = 0; j < D; ++j) { float2 q = p[j]; f[2*j] = q.x; f[2*j+1] = q.y; }
        #pragma unroll
        for (int i = 0; i < D; ++i) {
            int R = i * ROWS + row;
            int idx = (R * U + u0) ^ ((R & 7) << 3);
            *reinterpret_cast<unsigned*>(&lds[idx]) = pk2(f[i], f[D + i]);
        }
    }
    __syncthreads();

    v4f acc[MT][NPW];
    const int kcol = (lane >> 4) << 3;
    const int wcol = lane & 15;
    const int g4   = (lane >> 4) << 2;

    auto run_layer = [&](const unsigned short* __restrict__ wt) {
        #pragma unroll
        for (int mt = 0; mt < MT; ++mt)
            #pragma unroll
            for (int nt = 0; nt < NPW; ++nt) {
                v4f z = {0.f, 0.f, 0.f, 0.f};
                acc[mt][nt] = z;
            }
        #pragma unroll
        for (int kt = 0; kt < KT; ++kt) {
            v8bf b[NPW];
            #pragma unroll
            for (int nt = 0; nt < NPW; ++nt) {
                int w = (wid * NPW + nt) * 16 + wcol;
                b[nt] = *reinterpret_cast<const v8bf*>(wt + w * U + kt * 32 + kcol);
            }
            #pragma unroll
            for (int mt = 0; mt < MT; ++mt) {
                int R = mt * 16 + wcol;
                int idx = (R * U + kt * 32 + kcol) ^ ((R & 7) << 3);
                v8bf a = *reinterpret_cast<const v8bf*>(&lds[idx]);
                #pragma unroll
                for (int nt = 0; nt < NPW; ++nt)
                    acc[mt][nt] = __builtin_amdgcn_mfma_f32_16x16x32_bf16(
                        a, b[nt], acc[mt][nt], 0, 0, 0);
            }
        }
    };

    run_layer(wt0);
    __syncthreads();

    #pragma unroll
    for (int nt = 0; nt < NPW; ++nt) {
        int w = (wid * NPW + nt) * 16 + wcol;
        #pragma unroll
        for (int h = 0; h < NR16; ++h) {
            #pragma unroll
            for (int r = 0; r < 4; ++r) {
                float s = 0.f;
                #pragma unroll
                for (int i = 0; i < D; ++i) {
                    float v = acc[i * NR16 + h][nt][r];
                    s += v * v;
                }
                float fac = phi_from_sq(s);
                int n = h * 16 + g4 + r;
                #pragma unroll
                for (int i = 0; i < D; ++i) {
                    int R = i * ROWS + n;
                    int idx = (R * U + w) ^ ((R & 7) << 3);
                    lds[idx] = f2bf(acc[i * NR16 + h][nt][r] * fac);
                }
            }
        }
    }
    __syncthreads();

    run_layer(wt1);

    #pragma unroll
    for (int nt = 0; nt < NPW; ++nt) {
        int w = (wid * NPW + nt) * 16 + wcol;
        #pragma unroll
        for (int h = 0; h < NR16; ++h) {
            #pragma unroll
            for (int r = 0; r < 4; ++r) {
                int n = row0 + h * 16 + g4 + r;
                float* po = out + (long)n * 960 + OFF + w * D;
                #pragma unroll
                for (int i = 0; i < D; ++i)
                    po[i] = acc[i * NR16 + h][nt][r];
            }
        }
    }
}

// --- merged kernel ------------------------------------------------------------
// bid 0..1023    : l=0 (64 rows/block, 4 independent 16-row waves, no barriers)
// bid 1024..3071 : l=1 (32-row tiles)
// bid 3072..5119 : l=2 (32-row tiles)
__global__ __launch_bounds__(256, 4) void fused_all(
    const float* __restrict__ x,
    const unsigned short* __restrict__ ws,
    float* __restrict__ out)
{
    __shared__ unsigned short lds[16384];   // 32 KB
    int bid = blockIdx.x;
    if (bid < 1024)
        l0_wave(x, ws + 0, ws + 86016, out,
                lds + (threadIdx.x >> 6) * 4096, bid);
    else if (bid < 3072)
        irrep_block<128, 3, 256>(x, ws + 65536, ws + 151552, out, lds, bid - 1024);
    else
        irrep_block< 64, 5, 640>(x, ws + 81920, ws + 167936, out, lds, bid - 3072);
}

extern "C" void kernel_launch(void* const* d_in, const int* in_sizes, int n_in,
                              void* d_out, int out_size, void* d_ws, size_t ws_size,
                              hipStream_t stream)
{
    const float* x  = (const float*)d_in[0];
    const float* W0 = (const float*)d_in[1];  // 256x256
    const float* W1 = (const float*)d_in[2];  // 128x128
    const float* W2 = (const float*)d_in[3];  // 64x64
    const float* W3 = (const float*)d_in[4];  // 256x256
    const float* W4 = (const float*)d_in[5];  // 128x128
    const float* W5 = (const float*)d_in[6];  // 64x64
    unsigned short* ws = (unsigned short*)d_ws;   // 344064 B of bf16 WT
    float* out = (float*)d_out;

    wt_prep<<<672, 256, 0, stream>>>(W0, W1, W2, W3, W4, W5, ws);
    fused_all<<<5120, 256, 0, stream>>>(x, ws, out);
}

// Round 9
// 178.450 us; speedup vs baseline: 2.0090x; 1.4029x over previous
//
#include <hip/hip_runtime.h>

// irreps: 256x0e + 128x1e + 64x2e ; x row = 960 fp32
// Merged kernel (R5 structure, occupancy-tuned correctly this time):
// per-irrep fused linear -> normact -> linear, bf16 MFMA, A = x/H rows from
// LDS (XOR-swizzled), B = weight fragments streamed from L2.
// R9: l=0 ROWS=32 (16 KB), l=1 ROWS=16 (12 KB), l=2 ROWS=16 (10 KB) -- every
// path fits the 16 KB LDS allocation (R8 overflowed it: 24/20 KB in a 16 KB
// array). __launch_bounds__(256,6) -> VGPR<=85, 6 blocks/CU.

typedef __bf16 v8bf  __attribute__((ext_vector_type(8)));
typedef float  v4f   __attribute__((ext_vector_type(4)));
typedef unsigned short u16x8 __attribute__((ext_vector_type(8)));

__device__ __forceinline__ unsigned short f2bf(float x) {
    union { float f; unsigned u; } v; v.f = x;
    unsigned r = v.u + 0x7FFFu + ((v.u >> 16) & 1u);   // RNE (finite inputs)
    return (unsigned short)(r >> 16);
}
__device__ __forceinline__ unsigned pk2(float a, float b) {
    return (unsigned)f2bf(a) | ((unsigned)f2bf(b) << 16);
}

// Phi(n) = 0.5*(1+erf(n/sqrt(2))) = gelu(n)/n, n>=0.  A&S 7.1.26.
__device__ __forceinline__ float phi_from_sq(float s) {
    float n = __builtin_amdgcn_sqrtf(s);
    float z = n * 0.70710678118654752f;
    float t = __builtin_amdgcn_rcpf(fmaf(0.3275911f, z, 1.0f));
    float p = t * fmaf(t, fmaf(t, fmaf(t, fmaf(t, 1.061405429f, -1.453152027f),
                                       1.421413741f), -0.284496736f), 0.254829592f);
    float e = __builtin_amdgcn_exp2f(z * z * -1.4426950408889634f);
    return fmaf(p * e, -0.5f, 1.0f);
}

// --- pre-pass: W[u][w] fp32 -> WT[w][u] bf16, scaled by 1/sqrt(mul_in) -------
__global__ __launch_bounds__(256) void wt_prep(
    const float* __restrict__ w0, const float* __restrict__ w1,
    const float* __restrict__ w2, const float* __restrict__ w3,
    const float* __restrict__ w4, const float* __restrict__ w5,
    unsigned short* __restrict__ out)
{
    int t = blockIdx.x * 256 + threadIdx.x;
    if (t >= 172032) return;
    int s = (t < 65536) ? 0 : (t < 81920) ? 1 : (t < 86016) ? 2
          : (t < 151552) ? 3 : (t < 167936) ? 4 : 5;
    int base = (s == 0) ? 0 : (s == 1) ? 65536 : (s == 2) ? 81920
             : (s == 3) ? 86016 : (s == 4) ? 151552 : 167936;
    int lg   = (s == 0 || s == 3) ? 8 : (s == 1 || s == 4) ? 7 : 6;
    float scl = (s == 0 || s == 3) ? 0.0625f
              : (s == 1 || s == 4) ? 0.08838834764831845f : 0.125f;
    const float* p = (s == 0) ? w0 : (s == 1) ? w1 : (s == 2) ? w2
                   : (s == 3) ? w3 : (s == 4) ? w4 : w5;
    int loc = t - base;
    int w = loc >> lg;
    int u = loc & ((1 << lg) - 1);
    out[t] = f2bf(p[(u << lg) + w] * scl);
}

// --- per-irrep worker (ROWS-row tile) ----------------------------------------
// LDS: bf16 planes [i][n(ROWS)][u(U)], XOR-swizzled idx ^= (R&7)<<3, R=i*ROWS+n.
// LDS element count = ROWS*D*U  (l=0: 8192, l=1: 6144, l=2: 5120 -- all <=8192).
template<int U, int D, int OFF, int ROWS>
__device__ __forceinline__ void irrep_block(
    const float* __restrict__ x,
    const unsigned short* __restrict__ wt0,
    const unsigned short* __restrict__ wt1,
    float* __restrict__ out,
    unsigned short* __restrict__ lds,
    int tile)
{
    constexpr int MT   = (ROWS * D) / 16;   // m-tiles
    constexpr int NPW  = U / 64;            // n-tiles per wave (4 waves split n)
    constexpr int KT   = U / 32;            // k-steps
    constexpr int NR16 = ROWS / 16;         // 16-row groups per i-plane
    static_assert(ROWS * D * U <= 8192, "LDS overflow");

    const int tid  = threadIdx.x;
    const int lane = tid & 63;
    const int wid  = tid >> 6;
    const int row0 = tile * ROWS;

    // ---- stage x -> LDS bf16, de-interleaved [i*ROWS+n][u] ----
    if constexpr (D == 1) {
        #pragma unroll
        for (int o = 0; o < (ROWS * (U / 8)) / 256; ++o) {
            int oct = o * 256 + tid;
            int row = oct / (U / 8);
            int u0  = (oct % (U / 8)) * 8;
            const float4* p =
                reinterpret_cast<const float4*>(x + (long)(row0 + row) * 960 + OFF + u0);
            float4 fa = p[0], fb = p[1];
            u16x8 hv = { f2bf(fa.x), f2bf(fa.y), f2bf(fa.z), f2bf(fa.w),
                         f2bf(fb.x), f2bf(fb.y), f2bf(fb.z), f2bf(fb.w) };
            int idx = (row * U + u0) ^ ((row & 7) << 3);
            *reinterpret_cast<u16x8*>(&lds[idx]) = hv;
        }
    } else {
        constexpr int PAIRS = U / 2;
        #pragma unroll
        for (int g = 0; g < (ROWS * PAIRS) / 256; ++g) {
            int gid = g * 256 + tid;
            int row = gid / PAIRS;
            int u0  = (gid % PAIRS) * 2;
            const float2* p = reinterpret_cast<const float2*>(
                x + (long)(row0 + row) * 960 + OFF + u0 * D);
            float f[2 * D];
            #pragma unroll
            for (int j = 0; j < D; ++j) { float2 q = p[j]; f[2*j] = q.x; f[2*j+1] = q.y; }
            #pragma unroll
            for (int i = 0; i < D; ++i) {
                int R = i * ROWS + row;
                int idx = (R * U + u0) ^ ((R & 7) << 3);
                *reinterpret_cast<unsigned*>(&lds[idx]) = pk2(f[i], f[D + i]);
            }
        }
    }
    __syncthreads();

    v4f acc[MT][NPW];
    const int kcol = (lane >> 4) << 3;
    const int wcol = lane & 15;
    const int g4   = (lane >> 4) << 2;

    auto run_layer = [&](const unsigned short* __restrict__ wt) {
        #pragma unroll
        for (int mt = 0; mt < MT; ++mt)
            #pragma unroll
            for (int nt = 0; nt < NPW; ++nt) {
                v4f z = {0.f, 0.f, 0.f, 0.f};
                acc[mt][nt] = z;
            }
        #pragma unroll
        for (int kt = 0; kt < KT; ++kt) {
            v8bf b[NPW];
            #pragma unroll
            for (int nt = 0; nt < NPW; ++nt) {
                int w = (wid * NPW + nt) * 16 + wcol;
                b[nt] = *reinterpret_cast<const v8bf*>(wt + w * U + kt * 32 + kcol);
            }
            #pragma unroll
            for (int mt = 0; mt < MT; ++mt) {
                int R = mt * 16 + wcol;
                int idx = (R * U + kt * 32 + kcol) ^ ((R & 7) << 3);
                v8bf a = *reinterpret_cast<const v8bf*>(&lds[idx]);
                #pragma unroll
                for (int nt = 0; nt < NPW; ++nt)
                    acc[mt][nt] = __builtin_amdgcn_mfma_f32_16x16x32_bf16(
                        a, b[nt], acc[mt][nt], 0, 0, 0);
            }
        }
    };

    run_layer(wt0);
    __syncthreads();   // all layer-1 LDS reads done before H overwrites x

    // ---- norm-act: acc[i*NR16+h][nt][r] holds component i of row (h*16+g4+r) ----
    #pragma unroll
    for (int nt = 0; nt < NPW; ++nt) {
        int w = (wid * NPW + nt) * 16 + wcol;
        #pragma unroll
        for (int h = 0; h < NR16; ++h) {
            #pragma unroll
            for (int r = 0; r < 4; ++r) {
                float s = 0.f;
                #pragma unroll
                for (int i = 0; i < D; ++i) {
                    float v = acc[i * NR16 + h][nt][r];
                    s += v * v;
                }
                float fac = phi_from_sq(s);
                int n = h * 16 + g4 + r;
                #pragma unroll
                for (int i = 0; i < D; ++i) {
                    int R = i * ROWS + n;
                    int idx = (R * U + w) ^ ((R & 7) << 3);
                    lds[idx] = f2bf(acc[i * NR16 + h][nt][r] * fac);
                }
            }
        }
    }
    __syncthreads();

    run_layer(wt1);

    // ---- store fp32 at out[n][OFF + w*D + i]; lanes -> consecutive w ----
    #pragma unroll
    for (int nt = 0; nt < NPW; ++nt) {
        int w = (wid * NPW + nt) * 16 + wcol;
        #pragma unroll
        for (int h = 0; h < NR16; ++h) {
            #pragma unroll
            for (int r = 0; r < 4; ++r) {
                int n = row0 + h * 16 + g4 + r;
                float* po = out + (long)n * 960 + OFF + w * D;
                #pragma unroll
                for (int i = 0; i < D; ++i)
                    po[i] = acc[i * NR16 + h][nt][r];
            }
        }
    }
}

// --- merged kernel: contiguous type ranges ------------------------------------
// bid 0..2047     : l=0 (32-row tiles, 2048 tiles)
// bid 2048..6143  : l=1 (16-row tiles, 4096 tiles)
// bid 6144..10239 : l=2 (16-row tiles, 4096 tiles)
__global__ __launch_bounds__(256, 6) void fused_all(
    const float* __restrict__ x,
    const unsigned short* __restrict__ ws,
    float* __restrict__ out)
{
    __shared__ unsigned short lds[8192];   // 16 KB (max over the 3 types)
    int bid = blockIdx.x;
    if (bid < 2048)
        irrep_block<256, 1,   0, 32>(x, ws + 0,     ws + 86016,  out, lds, bid);
    else if (bid < 6144)
        irrep_block<128, 3, 256, 16>(x, ws + 65536, ws + 151552, out, lds, bid - 2048);
    else
        irrep_block< 64, 5, 640, 16>(x, ws + 81920, ws + 167936, out, lds, bid - 6144);
}

extern "C" void kernel_launch(void* const* d_in, const int* in_sizes, int n_in,
                              void* d_out, int out_size, void* d_ws, size_t ws_size,
                              hipStream_t stream)
{
    const float* x  = (const float*)d_in[0];
    const float* W0 = (const float*)d_in[1];  // 256x256
    const float* W1 = (const float*)d_in[2];  // 128x128
    const float* W2 = (const float*)d_in[3];  // 64x64
    const float* W3 = (const float*)d_in[4];  // 256x256
    const float* W4 = (const float*)d_in[5];  // 128x128
    const float* W5 = (const float*)d_in[6];  // 64x64
    unsigned short* ws = (unsigned short*)d_ws;   // 344064 B of bf16 WT
    float* out = (float*)d_out;

    wt_prep<<<672, 256, 0, stream>>>(W0, W1, W2, W3, W4, W5, ws);
    fused_all<<<10240, 256, 0, stream>>>(x, ws, out);
}

// Round 10
// 141.744 us; speedup vs baseline: 2.5293x; 1.2590x over previous
//
#include <hip/hip_runtime.h>

// irreps: 256x0e + 128x1e + 64x2e ; x row = 960 fp32
// Merged kernel (R5 structure + register B-prefetch):
// per-irrep fused linear -> normact -> linear, bf16 MFMA,
// A = x/H rows from LDS (XOR-swizzled), B = weight fragments from L2 with
// distance-1 register prefetch; kstep-0 fragments pre-issued across the
// preceding barrier so the L2 round trip hides under staging / normact.
// l=0: 64-row tiles; l=1,l=2: 32-row tiles (R5-proven geometry).

typedef __bf16 v8bf  __attribute__((ext_vector_type(8)));
typedef float  v4f   __attribute__((ext_vector_type(4)));
typedef unsigned short u16x8 __attribute__((ext_vector_type(8)));

__device__ __forceinline__ unsigned short f2bf(float x) {
    union { float f; unsigned u; } v; v.f = x;
    unsigned r = v.u + 0x7FFFu + ((v.u >> 16) & 1u);   // RNE (finite inputs)
    return (unsigned short)(r >> 16);
}
__device__ __forceinline__ unsigned pk2(float a, float b) {
    return (unsigned)f2bf(a) | ((unsigned)f2bf(b) << 16);
}

// Phi(n) = 0.5*(1+erf(n/sqrt(2))) = gelu(n)/n, n>=0.  A&S 7.1.26.
__device__ __forceinline__ float phi_from_n(float n) {
    float z = n * 0.70710678118654752f;
    float t = __builtin_amdgcn_rcpf(fmaf(0.3275911f, z, 1.0f));
    float p = t * fmaf(t, fmaf(t, fmaf(t, fmaf(t, 1.061405429f, -1.453152027f),
                                       1.421413741f), -0.284496736f), 0.254829592f);
    float e = __builtin_amdgcn_exp2f(z * z * -1.4426950408889634f);
    return fmaf(p * e, -0.5f, 1.0f);
}

// --- pre-pass: W[u][w] fp32 -> WT[w][u] bf16, scaled by 1/sqrt(mul_in) -------
__global__ __launch_bounds__(256) void wt_prep(
    const float* __restrict__ w0, const float* __restrict__ w1,
    const float* __restrict__ w2, const float* __restrict__ w3,
    const float* __restrict__ w4, const float* __restrict__ w5,
    unsigned short* __restrict__ out)
{
    int t = blockIdx.x * 256 + threadIdx.x;
    if (t >= 172032) return;
    int s = (t < 65536) ? 0 : (t < 81920) ? 1 : (t < 86016) ? 2
          : (t < 151552) ? 3 : (t < 167936) ? 4 : 5;
    int base = (s == 0) ? 0 : (s == 1) ? 65536 : (s == 2) ? 81920
             : (s == 3) ? 86016 : (s == 4) ? 151552 : 167936;
    int lg   = (s == 0 || s == 3) ? 8 : (s == 1 || s == 4) ? 7 : 6;
    float scl = (s == 0 || s == 3) ? 0.0625f
              : (s == 1 || s == 4) ? 0.08838834764831845f : 0.125f;
    const float* p = (s == 0) ? w0 : (s == 1) ? w1 : (s == 2) ? w2
                   : (s == 3) ? w3 : (s == 4) ? w4 : w5;
    int loc = t - base;
    int w = loc >> lg;
    int u = loc & ((1 << lg) - 1);
    out[t] = f2bf(p[(u << lg) + w] * scl);
}

// --- per-irrep worker (ROWS-row tile) ----------------------------------------
// LDS: bf16 planes [i][n(ROWS)][u(U)], XOR-swizzled idx ^= (R&7)<<3, R=i*ROWS+n.
template<int U, int D, int OFF, int ROWS>
__device__ __forceinline__ void irrep_block(
    const float* __restrict__ x,
    const unsigned short* __restrict__ wt0,
    const unsigned short* __restrict__ wt1,
    float* __restrict__ out,
    unsigned short* __restrict__ lds,
    int tile)
{
    constexpr int MT   = (ROWS * D) / 16;   // m-tiles
    constexpr int NPW  = U / 64;            // n-tiles per wave (4 waves split n)
    constexpr int KT   = U / 32;            // k-steps
    constexpr int NR16 = ROWS / 16;         // 16-row groups per i-plane
    static_assert(ROWS * D * U <= 16384, "LDS overflow");

    const int tid  = threadIdx.x;
    const int lane = tid & 63;
    const int wid  = tid >> 6;
    const int row0 = tile * ROWS;
    const int wcol = lane & 15;
    const int kcol = (lane >> 4) << 3;
    const int g4   = (lane >> 4) << 2;

    // ---- stage x -> LDS bf16, de-interleaved [i*ROWS+n][u] ----
    if constexpr (D == 1) {
        #pragma unroll
        for (int o = 0; o < (ROWS * (U / 8)) / 256; ++o) {
            int oct = o * 256 + tid;
            int row = oct / (U / 8);
            int u0  = (oct % (U / 8)) * 8;
            const float4* p =
                reinterpret_cast<const float4*>(x + (long)(row0 + row) * 960 + OFF + u0);
            float4 fa = p[0], fb = p[1];
            u16x8 hv = { f2bf(fa.x), f2bf(fa.y), f2bf(fa.z), f2bf(fa.w),
                         f2bf(fb.x), f2bf(fb.y), f2bf(fb.z), f2bf(fb.w) };
            int idx = (row * U + u0) ^ ((row & 7) << 3);
            *reinterpret_cast<u16x8*>(&lds[idx]) = hv;
        }
    } else {
        constexpr int PAIRS = U / 2;
        #pragma unroll
        for (int g = 0; g < (ROWS * PAIRS) / 256; ++g) {
            int gid = g * 256 + tid;
            int row = gid / PAIRS;
            int u0  = (gid % PAIRS) * 2;
            const float2* p = reinterpret_cast<const float2*>(
                x + (long)(row0 + row) * 960 + OFF + u0 * D);
            float f[2 * D];
            #pragma unroll
            for (int j = 0; j < D; ++j) { float2 q = p[j]; f[2*j] = q.x; f[2*j+1] = q.y; }
            #pragma unroll
            for (int i = 0; i < D; ++i) {
                int R = i * ROWS + row;
                int idx = (R * U + u0) ^ ((R & 7) << 3);
                *reinterpret_cast<unsigned*>(&lds[idx]) = pk2(f[i], f[D + i]);
            }
        }
    }

    v4f acc[MT][NPW];
    v8bf bpre[NPW];      // in-flight B fragments (function scope, static idx)

    auto issueB = [&](const unsigned short* __restrict__ wt, int kt) {
        #pragma unroll
        for (int nt = 0; nt < NPW; ++nt) {
            int w = (wid * NPW + nt) * 16 + wcol;
            bpre[nt] = *reinterpret_cast<const v8bf*>(wt + w * U + kt * 32 + kcol);
        }
    };

    auto run_layer = [&](const unsigned short* __restrict__ wt) {
        #pragma unroll
        for (int mt = 0; mt < MT; ++mt)
            #pragma unroll
            for (int nt = 0; nt < NPW; ++nt) {
                v4f z = {0.f, 0.f, 0.f, 0.f};
                acc[mt][nt] = z;
            }
        #pragma unroll
        for (int kt = 0; kt < KT; ++kt) {
            v8bf bcur[NPW];
            #pragma unroll
            for (int nt = 0; nt < NPW; ++nt) bcur[nt] = bpre[nt];
            if (kt + 1 < KT) issueB(wt, kt + 1);   // distance-1 prefetch
            #pragma unroll
            for (int mt = 0; mt < MT; ++mt) {
                int R = mt * 16 + wcol;
                int idx = (R * U + kt * 32 + kcol) ^ ((R & 7) << 3);
                v8bf a = *reinterpret_cast<const v8bf*>(&lds[idx]);
                #pragma unroll
                for (int nt = 0; nt < NPW; ++nt)
                    acc[mt][nt] = __builtin_amdgcn_mfma_f32_16x16x32_bf16(
                        a, bcur[nt], acc[mt][nt], 0, 0, 0);
            }
        }
    };

    issueB(wt0, 0);      // L2 round trip overlaps staging writes + barrier skew
    __syncthreads();     // stage visible

    run_layer(wt0);
    __syncthreads();     // all layer-1 LDS reads done before H overwrites x

    issueB(wt1, 0);      // layer-2 kstep-0 fragments fly under normact

    // ---- norm-act: acc[i*NR16+h][nt][r] holds component i of row (h*16+g4+r) ----
    #pragma unroll
    for (int nt = 0; nt < NPW; ++nt) {
        int w = (wid * NPW + nt) * 16 + wcol;
        #pragma unroll
        for (int h = 0; h < NR16; ++h) {
            #pragma unroll
            for (int r = 0; r < 4; ++r) {
                float n;
                if constexpr (D == 1) {
                    n = __builtin_fabsf(acc[h][nt][r]);
                } else {
                    float s = 0.f;
                    #pragma unroll
                    for (int i = 0; i < D; ++i) {
                        float v = acc[i * NR16 + h][nt][r];
                        s += v * v;
                    }
                    n = __builtin_amdgcn_sqrtf(s);
                }
                float fac = phi_from_n(n);
                int nr = h * 16 + g4 + r;
                #pragma unroll
                for (int i = 0; i < D; ++i) {
                    int R = i * ROWS + nr;
                    int idx = (R * U + w) ^ ((R & 7) << 3);
                    lds[idx] = f2bf(acc[i * NR16 + h][nt][r] * fac);
                }
            }
        }
    }
    __syncthreads();     // H visible

    run_layer(wt1);

    // ---- store fp32 at out[n][OFF + w*D + i]; lanes -> consecutive w ----
    #pragma unroll
    for (int nt = 0; nt < NPW; ++nt) {
        int w = (wid * NPW + nt) * 16 + wcol;
        #pragma unroll
        for (int h = 0; h < NR16; ++h) {
            #pragma unroll
            for (int r = 0; r < 4; ++r) {
                int n = row0 + h * 16 + g4 + r;
                float* po = out + (long)n * 960 + OFF + w * D;
                #pragma unroll
                for (int i = 0; i < D; ++i)
                    po[i] = acc[i * NR16 + h][nt][r];
            }
        }
    }
}

// --- merged kernel: contiguous type ranges (R5 geometry) ---------------------
// bid 0..1023    : l=0, 64-row tiles
// bid 1024..3071 : l=1, 32-row tiles
// bid 3072..5119 : l=2, 32-row tiles
__global__ __launch_bounds__(256, 4) void fused_all(
    const float* __restrict__ x,
    const unsigned short* __restrict__ ws,
    float* __restrict__ out)
{
    __shared__ unsigned short lds[16384];   // 32 KB (max over the 3 types)
    int bid = blockIdx.x;
    if (bid < 1024)
        irrep_block<256, 1,   0, 64>(x, ws + 0,     ws + 86016,  out, lds, bid);
    else if (bid < 3072)
        irrep_block<128, 3, 256, 32>(x, ws + 65536, ws + 151552, out, lds, bid - 1024);
    else
        irrep_block< 64, 5, 640, 32>(x, ws + 81920, ws + 167936, out, lds, bid - 3072);
}

extern "C" void kernel_launch(void* const* d_in, const int* in_sizes, int n_in,
                              void* d_out, int out_size, void* d_ws, size_t ws_size,
                              hipStream_t stream)
{
    const float* x  = (const float*)d_in[0];
    const float* W0 = (const float*)d_in[1];  // 256x256
    const float* W1 = (const float*)d_in[2];  // 128x128
    const float* W2 = (const float*)d_in[3];  // 64x64
    const float* W3 = (const float*)d_in[4];  // 256x256
    const float* W4 = (const float*)d_in[5];  // 128x128
    const float* W5 = (const float*)d_in[6];  // 64x64
    unsigned short* ws = (unsigned short*)d_ws;   // 344064 B of bf16 WT
    float* out = (float*)d_out;

    wt_prep<<<672, 256, 0, stream>>>(W0, W1, W2, W3, W4, W5, ws);
    fused_all<<<5120, 256, 0, stream>>>(x, ws, out);
}